// Round 1
// baseline (607.503 us; speedup 1.0000x reference)
//
#include <hip/hip_runtime.h>
#include <cstdint>
#include <cstddef>

#define DIM 4096
#define SEQ 2048
#define NH 32
#define NKV 8
#define HD 128
#define QKVN 6144

typedef __bf16 bf16_t;
typedef __bf16 bf16x8 __attribute__((ext_vector_type(8)));
typedef __bf16 bf16x4 __attribute__((ext_vector_type(4)));
typedef __bf16 bf16x2 __attribute__((ext_vector_type(2)));
typedef float f32x4 __attribute__((ext_vector_type(4)));
typedef int int4v __attribute__((ext_vector_type(4)));

__device__ __forceinline__ f32x4 mfma16(bf16x8 a, bf16x8 b, f32x4 c) {
  return __builtin_amdgcn_mfma_f32_16x16x32_bf16(a, b, c, 0, 0, 0);
}

__device__ __forceinline__ void async16(const bf16_t* g, bf16_t* l) {
  __builtin_amdgcn_global_load_lds((__attribute__((address_space(1))) void*)g,
                                   (__attribute__((address_space(3))) void*)l,
                                   16, 0, 0);
}

__device__ __forceinline__ int pack2(float a, float b) {
  bf16x2 h = { (bf16_t)a, (bf16_t)b };
  return __builtin_bit_cast(int, h);
}

// rule #18: inline-asm lgkmcnt(0) must be followed by sched_barrier(0)
#define LGKM0() do { asm volatile("s_waitcnt lgkmcnt(0)" ::: "memory"); \
                     __builtin_amdgcn_sched_barrier(0); } while (0)
#define VM0() do { asm volatile("s_waitcnt vmcnt(0)" ::: "memory"); } while (0)

// ---------------- cast x (fp32 -> bf16), 4 elems/thread ----------------
__global__ void cast_x(const float* __restrict__ x, bf16_t* __restrict__ xb) {
  int i = blockIdx.x * 256 + threadIdx.x;
  const float4 v = ((const float4*)x)[i];
  bf16x4 o = { (bf16_t)v.x, (bf16_t)v.y, (bf16_t)v.z, (bf16_t)v.w };
  *(bf16x4*)(xb + (size_t)i * 4) = o;
}

// ------- transpose-cast: src fp32 (Kdim x Ncols) -> dst bf16 (Ncols x Kdim) -------
__global__ void tcast(const float* __restrict__ src, bf16_t* __restrict__ dst,
                      int Ncols, int Kdim) {
  __shared__ float tile[32][33];
  int n0 = blockIdx.x * 32, k0 = blockIdx.y * 32;
  int tx = threadIdx.x, ty = threadIdx.y;  // 32 x 8
#pragma unroll
  for (int r = 0; r < 4; r++)
    tile[ty + 8 * r][tx] = src[(size_t)(k0 + ty + 8 * r) * Ncols + n0 + tx];
  __syncthreads();
#pragma unroll
  for (int r = 0; r < 4; r++)
    dst[(size_t)(n0 + ty + 8 * r) * Kdim + k0 + tx] = (bf16_t)tile[tx][ty + 8 * r];
}

// ---------------- GEMM: 256x256 tile, BK=64, 8 waves, 8-phase schedule --------
// C(MxN) fp32 = A(MxK) bf16 @ Bt(NxK)^T.  LDS 128 KiB (2 dbuf x 32 KiB x {A,B}),
// st_16x32 swizzle (byte ^= ((byte>>9)&1)<<5) applied as inverse-swizzled GLOBAL
// source (global_load_lds dest must stay linear) + swizzled ds_read column.
// Per K-tile: 4 phases x 16 MFMA; kt+1 staged during phases 0-1; vmcnt drained
// only at the K-tile boundary (loads have had >=3 phases to land).
__global__ __launch_bounds__(512) void gemm256(const bf16_t* __restrict__ A,
                                               const bf16_t* __restrict__ Bt,
                                               float* __restrict__ C,
                                               int M, int N, int K) {
  __shared__ bf16_t As[2][16384];
  __shared__ bf16_t Bs[2][16384];
  const int t = threadIdx.x;
  const int lane = t & 63;
  const int l15 = lane & 15, quad = lane >> 4;
  const int w = t >> 6, wm = w >> 2, wn = w & 3;  // 2 x 4 wave grid

  // bijective XCD swizzle (nwg % 8 == 0 for both call sites):
  // XCD c owns one full M-row strip -> A panel (2 MB) stays L2-resident.
  const int gx = gridDim.x;
  const int nwg = gx * gridDim.y;
  const int id = blockIdx.y * gx + blockIdx.x;
  const int swz = (id & 7) * (nwg >> 3) + (id >> 3);
  const int bm = (swz / gx) * 256, bn = (swz % gx) * 256;

  // staging source: thread t -> half-tile row t>>3 (+i*64,+h*128), cols
  // ((t&7)*8) ^ ((t>>1)&16)  == inverse st_16x32 swizzle (involution)
  const int srow = t >> 3;
  const int scol = ((t & 7) << 3) ^ ((t >> 1) & 16);
  const bf16_t* gA = A + (size_t)(bm + srow) * K + scol;
  const bf16_t* gB = Bt + (size_t)(bn + srow) * K + scol;
  const int ldst = t * 8;

  // fragment-read bases: element (r,c) lives at c ^ ((r&4)?16:0)
  const int qx = (quad * 8) ^ ((l15 & 4) ? 16 : 0);
  const int aBase = wm * 8192 + l15 * 64 + qx;
  const int bBase = (wn >> 1) * 8192 + ((wn & 1) * 64 + l15) * 64 + qx;

  f32x4 acc[8][4] = {};
  bf16x8 af[4][2], bfr[2][2];

  // prologue: stage kt0 -> buf0, drain (startup only)
#pragma unroll
  for (int h = 0; h < 2; h++)
#pragma unroll
    for (int i = 0; i < 2; i++) {
      async16(gA + (size_t)(h * 128 + i * 64) * K, &As[0][h * 8192 + i * 4096 + ldst]);
      async16(gB + (size_t)(h * 128 + i * 64) * K, &Bs[0][h * 8192 + i * 4096 + ldst]);
    }
  VM0();
  __builtin_amdgcn_s_barrier();

  const int nkt = K >> 6;
  for (int kt = 0; kt < nkt; ++kt) {
    const int buf = kt & 1;
    const int k1 = (kt + 1) << 6;
    const bool pf = (kt + 1) < nkt;

    // ---- phase 0: mi 0-3 x ni 0-1 ; stage A-halves of kt+1 ----
#pragma unroll
    for (int mi = 0; mi < 4; mi++)
#pragma unroll
      for (int s = 0; s < 2; s++)
        af[mi][s] = *(const bf16x8*)&As[buf][aBase + mi * 1024 + s * 32];
#pragma unroll
    for (int ni = 0; ni < 2; ni++)
#pragma unroll
      for (int s = 0; s < 2; s++)
        bfr[ni][s] = *(const bf16x8*)&Bs[buf][bBase + ni * 1024 + s * 32];
    if (pf) {
#pragma unroll
      for (int h = 0; h < 2; h++)
#pragma unroll
        for (int i = 0; i < 2; i++)
          async16(gA + (size_t)(h * 128 + i * 64) * K + k1,
                  &As[buf ^ 1][h * 8192 + i * 4096 + ldst]);
    }
    __builtin_amdgcn_s_barrier();
    LGKM0();
    __builtin_amdgcn_s_setprio(1);
#pragma unroll
    for (int mi = 0; mi < 4; mi++)
#pragma unroll
      for (int ni = 0; ni < 2; ni++)
#pragma unroll
        for (int s = 0; s < 2; s++)
          acc[mi][ni] = mfma16(af[mi][s], bfr[ni][s], acc[mi][ni]);
    __builtin_amdgcn_s_setprio(0);
    __builtin_amdgcn_s_barrier();

    // ---- phase 1: mi 0-3 x ni 2-3 ; stage B-halves of kt+1 ----
#pragma unroll
    for (int ni = 0; ni < 2; ni++)
#pragma unroll
      for (int s = 0; s < 2; s++)
        bfr[ni][s] = *(const bf16x8*)&Bs[buf][bBase + (ni + 2) * 1024 + s * 32];
    if (pf) {
#pragma unroll
      for (int h = 0; h < 2; h++)
#pragma unroll
        for (int i = 0; i < 2; i++)
          async16(gB + (size_t)(h * 128 + i * 64) * K + k1,
                  &Bs[buf ^ 1][h * 8192 + i * 4096 + ldst]);
    }
    __builtin_amdgcn_s_barrier();
    LGKM0();
    __builtin_amdgcn_s_setprio(1);
#pragma unroll
    for (int mi = 0; mi < 4; mi++)
#pragma unroll
      for (int ni = 0; ni < 2; ni++)
#pragma unroll
        for (int s = 0; s < 2; s++)
          acc[mi][ni + 2] = mfma16(af[mi][s], bfr[ni][s], acc[mi][ni + 2]);
    __builtin_amdgcn_s_setprio(0);
    __builtin_amdgcn_s_barrier();

    // ---- phase 2: mi 4-7 x ni 2-3 (reuse bfr) ----
#pragma unroll
    for (int mi = 0; mi < 4; mi++)
#pragma unroll
      for (int s = 0; s < 2; s++)
        af[mi][s] = *(const bf16x8*)&As[buf][aBase + (mi + 4) * 1024 + s * 32];
    __builtin_amdgcn_s_barrier();
    LGKM0();
    __builtin_amdgcn_s_setprio(1);
#pragma unroll
    for (int mi = 0; mi < 4; mi++)
#pragma unroll
      for (int ni = 0; ni < 2; ni++)
#pragma unroll
        for (int s = 0; s < 2; s++)
          acc[mi + 4][ni + 2] = mfma16(af[mi][s], bfr[ni][s], acc[mi + 4][ni + 2]);
    __builtin_amdgcn_s_setprio(0);
    __builtin_amdgcn_s_barrier();

    // ---- phase 3: mi 4-7 x ni 0-1 (reuse af) ; boundary drain ----
#pragma unroll
    for (int ni = 0; ni < 2; ni++)
#pragma unroll
      for (int s = 0; s < 2; s++)
        bfr[ni][s] = *(const bf16x8*)&Bs[buf][bBase + ni * 1024 + s * 32];
    __builtin_amdgcn_s_barrier();
    LGKM0();
    __builtin_amdgcn_s_setprio(1);
#pragma unroll
    for (int mi = 0; mi < 4; mi++)
#pragma unroll
      for (int ni = 0; ni < 2; ni++)
#pragma unroll
        for (int s = 0; s < 2; s++)
          acc[mi + 4][ni] = mfma16(af[mi][s], bfr[ni][s], acc[mi + 4][ni]);
    __builtin_amdgcn_s_setprio(0);
    VM0();  // kt+1's 8 loads were issued 3-4 phases ago -> near-free drain
    __builtin_amdgcn_s_barrier();
  }

  // epilogue: C/D layout col=l15, row=quad*4+r (verified mapping)
#pragma unroll
  for (int mi = 0; mi < 8; mi++)
#pragma unroll
    for (int ni = 0; ni < 4; ni++) {
      size_t row = (size_t)bm + wm * 128 + mi * 16 + quad * 4;
      size_t col = (size_t)bn + wn * 64 + ni * 16 + l15;
#pragma unroll
      for (int r = 0; r < 4; r++)
        C[(row + r) * N + col] = acc[mi][ni][r];
    }
}

// ---------------- RoPE + scatter ----------------
// Q outputs pre-scaled by SCALE*log2(e) so attention uses exp2 directly.
// Vt is written with keys PERMUTED within each 32-key chunk:
//   slot s = ((t&12)<<1) + (t&3) + ((t&16)>>2)   (t = key mod 32)
// matching the PV B-fragment identity layout in attn_kernel.
__global__ void rope_scatter(const float* __restrict__ qkv, bf16_t* __restrict__ Qb,
                             bf16_t* __restrict__ Kb, bf16_t* __restrict__ Vt,
                             float* __restrict__ kOut, float* __restrict__ vOut) {
  int idx = blockIdx.x * 256 + threadIdx.x;
  int t = idx / 3072;
  int p = idx - t * 3072;
  const float NEG_L2T_64 = -0.20762050593046f;  // -log2(10000)/64
  const float SS = 0.08838834764831845f * 1.4426950408889634f;  // SCALE*log2(e)
  if (p < 2048) {  // Q
    int hh = p >> 6, pr = p & 63;
    int d0 = pr << 1;
    const float* src = qkv + (size_t)t * QKVN + hh * HD + d0;
    float a = src[0], b = src[1];
    int j0 = d0 & 63, j1 = (d0 + 1) & 63;
    float th0 = (float)t * exp2f((float)j0 * NEG_L2T_64);
    float th1 = (float)t * exp2f((float)j1 * NEG_L2T_64);
    float o0 = (a * cosf(th0) - b * sinf(th0)) * SS;
    float o1 = (b * cosf(th1) + a * sinf(th1)) * SS;
    bf16_t* dst = Qb + ((size_t)hh * SEQ + t) * HD + d0;
    dst[0] = (bf16_t)o0;
    dst[1] = (bf16_t)o1;
  } else if (p < 2560) {  // K
    int q2 = p - 2048;
    int kh = q2 >> 6, pr = q2 & 63;
    int d0 = pr << 1;
    const float* src = qkv + (size_t)t * QKVN + 4096 + kh * HD + d0;
    float a = src[0], b = src[1];
    int j0 = d0 & 63, j1 = (d0 + 1) & 63;
    float th0 = (float)t * exp2f((float)j0 * NEG_L2T_64);
    float th1 = (float)t * exp2f((float)j1 * NEG_L2T_64);
    float o0 = a * cosf(th0) - b * sinf(th0);
    float o1 = b * cosf(th1) + a * sinf(th1);
    bf16_t* dst = Kb + ((size_t)kh * SEQ + t) * HD + d0;
    dst[0] = (bf16_t)o0;
    dst[1] = (bf16_t)o1;
#pragma unroll
    for (int rep = 0; rep < 4; rep++) {
      float* kp = kOut + ((size_t)(kh * 4 + rep) * SEQ + t) * HD + d0;
      kp[0] = o0;
      kp[1] = o1;
    }
  } else {  // V
    int q2 = p - 2560;
    int kh = q2 >> 6, pr = q2 & 63;
    int d0 = pr << 1;
    const float* src = qkv + (size_t)t * QKVN + 5120 + kh * HD + d0;
    float a = src[0], b = src[1];
#pragma unroll
    for (int rep = 0; rep < 4; rep++) {
      float* vp = vOut + ((size_t)(kh * 4 + rep) * SEQ + t) * HD + d0;
      vp[0] = a;
      vp[1] = b;
    }
    // permuted key position for attention's PV slot ordering
    int tp = (t & ~31) + ((t & 12) << 1) + (t & 3) + ((t & 16) >> 2);
    Vt[((size_t)kh * HD + d0) * SEQ + tp] = (bf16_t)a;
    Vt[((size_t)kh * HD + d0 + 1) * SEQ + tp] = (bf16_t)b;
  }
}

// ---------------- Flash attention ----------------
// Grid: (8 q-tiles of 256 rows, 32 heads). 512 threads = 8 waves x 32 q-rows.
// S^T = K*Qs^T; fixed-max exp2 softmax; K/V (KT=64) double-buffered via
// global_load_lds. PV B-fragment is built IDENTITY from the lane's own S
// registers (slot order quad*8+j <-> lo/hi S-tile rows quad*4..); V was
// pre-permuted in rope_scatter to match.
__global__ __launch_bounds__(512, 2) void attn_kernel(const bf16_t* __restrict__ Qb,
                                                      const bf16_t* __restrict__ Kb,
                                                      const bf16_t* __restrict__ Vt,
                                                      bf16_t* __restrict__ AO) {
  __shared__ bf16_t Ks[2][8192];  // [buf][kc(4)][key(64)][d(32)]
  __shared__ bf16_t Vs[2][8192];  // [buf][kt(2)][d(128)][slot(32)]
  const int h = blockIdx.y, kh = h >> 2;
  const int qbase = blockIdx.x * 256;
  const int w = threadIdx.x >> 6, lane = threadIdx.x & 63;
  const int l15 = lane & 15, quad = lane >> 4;
  const bf16_t* KbH = Kb + (size_t)kh * SEQ * HD;
  const bf16_t* VtH = Vt + (size_t)kh * HD * SEQ;

  // persistent Q fragments: this wave's 32 q-rows (B-operand: n=q, k=d)
  bf16x8 qf[2][4];
#pragma unroll
  for (int nq = 0; nq < 2; nq++) {
    const bf16_t* qp = Qb + ((size_t)h * SEQ + qbase + w * 32 + nq * 16 + l15) * HD + quad * 8;
#pragma unroll
    for (int kc = 0; kc < 4; kc++) qf[nq][kc] = *(const bf16x8*)(qp + kc * 32);
  }

  f32x4 acc[8][2] = {};       // O^T: [d-tile][q-tile], d=quad*4+r, q=l15
  float rsum[2] = {0.f, 0.f};

  auto stage = [&](int buf, int kt0) {
    if (w < 4) {  // K tile: waves 0-3, one 32-d chunk each
      int kc = w;
#pragma unroll
      for (int kg = 0; kg < 4; kg++) {
        const bf16_t* g = KbH + (size_t)(kt0 + kg * 16 + (lane >> 2)) * HD + kc * 32 + (lane & 3) * 8;
        async16(g, &Ks[buf][kc * 2048 + kg * 512]);
      }
    } else {  // V tile: waves 4-7
      int vi = w - 4, kt = vi >> 1, dg0 = (vi & 1) * 4;
#pragma unroll
      for (int j = 0; j < 4; j++) {
        int dg = dg0 + j;
        const bf16_t* g = VtH + (size_t)(dg * 16 + (lane >> 2)) * SEQ + kt0 + kt * 32 + (lane & 3) * 8;
        async16(g, &Vs[buf][kt * 4096 + dg * 512]);
      }
    }
  };

  stage(0, 0);
  int buf = 0;

  for (int kt0 = 0; kt0 < SEQ; kt0 += 64, buf ^= 1) {
    __syncthreads();  // drains this wave's staging vmcnt; buf ready
    if (kt0 + 64 < SEQ) stage(buf ^ 1, kt0 + 64);

    // S^T = K * Qs^T  (A = K rows: m=key, k=d; B = Q rows: n=q, k=d)
    f32x4 sacc[4][2] = {};
#pragma unroll
    for (int mi = 0; mi < 4; mi++)
#pragma unroll
      for (int kc = 0; kc < 4; kc++) {
        bf16x8 kf = *(const bf16x8*)(&Ks[buf][(kc * 64 + mi * 16 + l15) * 32 + quad * 8]);
#pragma unroll
        for (int nq = 0; nq < 2; nq++)
          sacc[mi][nq] = mfma16(kf, qf[nq][kc], sacc[mi][nq]);
      }

    // p = exp2(s) (fixed max), per-lane partial row sums, pack to bf16 pairs
    int pk[4][2][2];
#pragma unroll
    for (int mi = 0; mi < 4; mi++)
#pragma unroll
      for (int nq = 0; nq < 2; nq++) {
        float p0 = exp2f(sacc[mi][nq][0]);
        float p1 = exp2f(sacc[mi][nq][1]);
        float p2 = exp2f(sacc[mi][nq][2]);
        float p3 = exp2f(sacc[mi][nq][3]);
        rsum[nq] += (p0 + p1) + (p2 + p3);
        pk[mi][nq][0] = pack2(p0, p1);
        pk[mi][nq][1] = pack2(p2, p3);
      }

    // PV: O^T += V_perm * P_slots. B-frag = lane's own registers (identity):
    // slot quad*8+j: j0..3 -> lo tile (mi=2kt) rows quad*4+j, j4..7 -> hi tile.
#pragma unroll
    for (int kt = 0; kt < 2; kt++) {
#pragma unroll
      for (int nq = 0; nq < 2; nq++) {
        int4v dw;
        dw[0] = pk[2 * kt][nq][0];
        dw[1] = pk[2 * kt][nq][1];
        dw[2] = pk[2 * kt + 1][nq][0];
        dw[3] = pk[2 * kt + 1][nq][1];
        bf16x8 pf = __builtin_bit_cast(bf16x8, dw);
#pragma unroll
        for (int dt = 0; dt < 8; dt++) {
          bf16x8 vf = *(const bf16x8*)(&Vs[buf][(kt * 128 + dt * 16 + l15) * 32 + quad * 8]);
          acc[dt][nq] = mfma16(vf, pf, acc[dt][nq]);
        }
      }
    }
  }

  // epilogue: finish row sums (reduce across quad lanes), normalize, store O
#pragma unroll
  for (int nq = 0; nq < 2; nq++) {
    float rs = rsum[nq];
    rs += __shfl_xor(rs, 16);
    rs += __shfl_xor(rs, 32);
    float inv = 1.0f / rs;
    int q = qbase + w * 32 + nq * 16 + l15;
#pragma unroll
    for (int dt = 0; dt < 8; dt++) {
      bf16x4 o = { (bf16_t)(acc[dt][nq][0] * inv), (bf16_t)(acc[dt][nq][1] * inv),
                   (bf16_t)(acc[dt][nq][2] * inv), (bf16_t)(acc[dt][nq][3] * inv) };
      *(bf16x4*)(AO + (size_t)q * DIM + h * HD + dt * 16 + quad * 4) = o;
    }
  }
}

extern "C" void kernel_launch(void* const* d_in, const int* in_sizes, int n_in,
                              void* d_out, int out_size, void* d_ws, size_t ws_size,
                              hipStream_t stream) {
  const float* x = (const float*)d_in[0];
  const float* wq = (const float*)d_in[1];
  const float* wk = (const float*)d_in[2];
  const float* wv = (const float*)d_in[3];
  const float* wo = (const float*)d_in[4];
  float* out = (float*)d_out;
  float* kOut = out + (size_t)SEQ * DIM;
  float* vOut = kOut + (size_t)NH * SEQ * HD;

  char* ws = (char*)d_ws;
  bf16_t* Xb = (bf16_t*)ws;                          // 16 MB; later aliased as AO
  bf16_t* WT = (bf16_t*)(ws + 16777216);             // 48 MB: [wq^T|wk^T|wv^T]
  float* QKV = (float*)(ws + 67108864);              // 48 MB fp32
  bf16_t* WoT = (bf16_t*)(ws + 67108864);            // alias (QKV dead by then)
  bf16_t* Qb = (bf16_t*)(ws + 117440512);            // 16 MB
  bf16_t* Kb = (bf16_t*)(ws + 134217728);            // 4 MB
  bf16_t* Vt = (bf16_t*)(ws + 138412032);            // 4 MB (slot-permuted keys)
  bf16_t* AO = Xb;

  dim3 tb(32, 8);
  cast_x<<<8192, 256, 0, stream>>>(x, Xb);
  tcast<<<dim3(128, 128), tb, 0, stream>>>(wq, WT, 4096, 4096);
  tcast<<<dim3(32, 128), tb, 0, stream>>>(wk, WT + (size_t)4096 * 4096, 1024, 4096);
  tcast<<<dim3(32, 128), tb, 0, stream>>>(wv, WT + (size_t)5120 * 4096, 1024, 4096);
  gemm256<<<dim3(24, 8), 512, 0, stream>>>(Xb, WT, QKV, 2048, 6144, 4096);
  rope_scatter<<<24576, 256, 0, stream>>>(QKV, Qb, Kb, Vt, kOut, vOut);
  tcast<<<dim3(128, 128), tb, 0, stream>>>(wo, WoT, 4096, 4096);
  attn_kernel<<<dim3(8, 32), 512, 0, stream>>>(Qb, Kb, Vt, AO);
  gemm256<<<dim3(16, 8), 512, 0, stream>>>(AO, WoT, out, 2048, 4096, 4096);
}

// Round 2
// 552.097 us; speedup vs baseline: 1.1004x; 1.1004x over previous
//
#include <hip/hip_runtime.h>
#include <cstdint>
#include <cstddef>

#define DIM 4096
#define SEQ 2048
#define NH 32
#define NKV 8
#define HD 128
#define QKVN 6144

typedef __bf16 bf16_t;
typedef __bf16 bf16x8 __attribute__((ext_vector_type(8)));
typedef __bf16 bf16x4 __attribute__((ext_vector_type(4)));
typedef __bf16 bf16x2 __attribute__((ext_vector_type(2)));
typedef float f32x4 __attribute__((ext_vector_type(4)));
typedef int int4v __attribute__((ext_vector_type(4)));

__device__ __forceinline__ f32x4 mfma16(bf16x8 a, bf16x8 b, f32x4 c) {
  return __builtin_amdgcn_mfma_f32_16x16x32_bf16(a, b, c, 0, 0, 0);
}

__device__ __forceinline__ void async16(const bf16_t* g, bf16_t* l) {
  __builtin_amdgcn_global_load_lds((__attribute__((address_space(1))) void*)g,
                                   (__attribute__((address_space(3))) void*)l,
                                   16, 0, 0);
}

__device__ __forceinline__ int pack2(float a, float b) {
  bf16x2 h = { (bf16_t)a, (bf16_t)b };
  return __builtin_bit_cast(int, h);
}

// rule #18: inline-asm waits must be followed by sched_barrier(0)
#define LGKM0() do { asm volatile("s_waitcnt lgkmcnt(0)" ::: "memory"); \
                     __builtin_amdgcn_sched_barrier(0); } while (0)

template <int N> __device__ __forceinline__ void vmw() {
  if constexpr (N == 3) asm volatile("s_waitcnt vmcnt(3)" ::: "memory");
  else if constexpr (N == 4) asm volatile("s_waitcnt vmcnt(4)" ::: "memory");
  else if constexpr (N == 5) asm volatile("s_waitcnt vmcnt(5)" ::: "memory");
  else if constexpr (N == 6) asm volatile("s_waitcnt vmcnt(6)" ::: "memory");
  __builtin_amdgcn_sched_barrier(0);
}

// ---------------- cast x (fp32 -> bf16), 4 elems/thread ----------------
__global__ void cast_x(const float* __restrict__ x, bf16_t* __restrict__ xb) {
  int i = blockIdx.x * 256 + threadIdx.x;
  const float4 v = ((const float4*)x)[i];
  bf16x4 o = { (bf16_t)v.x, (bf16_t)v.y, (bf16_t)v.z, (bf16_t)v.w };
  *(bf16x4*)(xb + (size_t)i * 4) = o;
}

// ------- transpose-cast: src fp32 (Kdim x Ncols) -> dst bf16 (Ncols x Kdim) -------
__global__ void tcast(const float* __restrict__ src, bf16_t* __restrict__ dst,
                      int Ncols, int Kdim) {
  __shared__ float tile[32][33];
  int n0 = blockIdx.x * 32, k0 = blockIdx.y * 32;
  int tx = threadIdx.x, ty = threadIdx.y;  // 32 x 8
#pragma unroll
  for (int r = 0; r < 4; r++)
    tile[ty + 8 * r][tx] = src[(size_t)(k0 + ty + 8 * r) * Ncols + n0 + tx];
  __syncthreads();
#pragma unroll
  for (int r = 0; r < 4; r++)
    dst[(size_t)(n0 + ty + 8 * r) * Kdim + k0 + tx] = (bf16_t)tile[tx][ty + 8 * r];
}

// ---------------- GEMM: 256 x (NF*64) tile, BK=64, 8 waves, 4-phase -----------
// C = A @ Bt^T.  LDS: A 2x32KB, B 2x(NF*8KB).  Full (row&7) XOR swizzle:
// LDS[r][cg] holds global col-group cg^(r&7) (linear DMA dest, pre-swizzled
// global source); reads XOR the same way -> balanced 8 dword-accesses/bank.
// Staging split into consumption-ordered batches b1={A0,A1,B0..B(NA-1)},
// b2={B(NF-1)}, b3={A2,A3}; counted vmcnt keeps loads in flight across the
// K-tile boundary (never drain to 0 in the main loop).
// Phase map: P0 = lo-mi x niA, P1 = lo x niB, P2 = hi x niB, P3 = hi x niA.
// Row maps: A row = (mi>>2)*128 + wm*64 + (mi&3)*16 + l15  (lo in g0/g1, hi g2/g3)
//           B row = ni*64 + wn*16 + l15                     (ni == group)
template <int NF>
__global__ __launch_bounds__(512) void gemm256(const bf16_t* __restrict__ A,
                                               const bf16_t* __restrict__ Bt,
                                               float* __restrict__ C,
                                               int M, int N, int K) {
  constexpr int NA = NF - 1;
  constexpr int S1 = 2 + NA;  // loads in batch 1
  __shared__ bf16_t As[2][16384];
  __shared__ bf16_t Bs[2][NF * 4096];
  const int t = threadIdx.x;
  const int lane = t & 63;
  const int l15 = lane & 15, quad = lane >> 4;
  const int w = t >> 6, wm = w >> 2, wn = w & 3;  // 2 x 4 wave grid
  const int cgx = l15 & 7;

  // bijective XCD swizzle (nwg == 256, %8 == 0): each XCD owns one M-strip.
  const int gx = gridDim.x;
  const int nwg = gx * gridDim.y;
  const int id = blockIdx.y * gx + blockIdx.x;
  const int swz = (id & 7) * (nwg >> 3) + (id >> 3);
  const int bm = (swz / gx) * 256, bn = (swz % gx) * (NF * 64);

  // staging: thread t -> row t>>3 within a 64-row group; LDS col-group t&7
  // holds global col-group (t&7)^(row&7)  (self-inverse swizzle)
  const int srow = t >> 3;
  const int scol = ((t & 7) ^ (srow & 7)) << 3;
  const bf16_t* gA = A + (size_t)(bm + srow) * K + scol;
  const bf16_t* gB = Bt + (size_t)(bn + srow) * K + scol;
  const int ldst = t * 8;

  f32x4 acc[8][NF] = {};
  bf16x8 af[4][2], bfa[NA][2], bfb[2];

  auto sb1 = [&](int b2, int kk) {
    async16(gA + kk, &As[b2][ldst]);
    async16(gA + (size_t)64 * K + kk, &As[b2][4096 + ldst]);
    async16(gB + kk, &Bs[b2][ldst]);
    if constexpr (NF == 3) async16(gB + (size_t)64 * K + kk, &Bs[b2][4096 + ldst]);
  };
  auto sb2 = [&](int b2, int kk) {
    async16(gB + (size_t)((NF - 1) * 64) * K + kk, &Bs[b2][(NF - 1) * 4096 + ldst]);
  };
  auto sb3 = [&](int b2, int kk) {
    async16(gA + (size_t)128 * K + kk, &As[b2][8192 + ldst]);
    async16(gA + (size_t)192 * K + kk, &As[b2][12288 + ldst]);
  };

  // prologue: stage tile 0, wait for batch 1 only
  sb1(0, 0);
  sb2(0, 0);
  sb3(0, 0);
  vmw<3>();
  __builtin_amdgcn_s_barrier();

  const int nkt = K >> 6;
  for (int kt = 0; kt < nkt; ++kt) {
    const int buf = kt & 1;
    const int k1 = (kt + 1) << 6;
    const bool pf = (kt + 1) < nkt;

    // ---- P0: lo-mi x niA ----
#pragma unroll
    for (int mi = 0; mi < 4; mi++)
#pragma unroll
      for (int s = 0; s < 2; s++)
        af[mi][s] = *(const bf16x8*)&As[buf][(wm * 64 + mi * 16 + l15) * 64 +
                                            (((s << 2) | quad) ^ cgx) * 8];
#pragma unroll
    for (int ni = 0; ni < NA; ni++)
#pragma unroll
      for (int s = 0; s < 2; s++)
        bfa[ni][s] = *(const bf16x8*)&Bs[buf][(ni * 64 + wn * 16 + l15) * 64 +
                                              (((s << 2) | quad) ^ cgx) * 8];
    if (pf) sb1(buf ^ 1, k1);
    __builtin_amdgcn_s_barrier();
    LGKM0();
    __builtin_amdgcn_s_setprio(1);
#pragma unroll
    for (int mi = 0; mi < 4; mi++)
#pragma unroll
      for (int ni = 0; ni < NA; ni++)
#pragma unroll
        for (int s = 0; s < 2; s++)
          acc[mi][ni] = mfma16(af[mi][s], bfa[ni][s], acc[mi][ni]);
    __builtin_amdgcn_s_setprio(0);
    vmw<2 + S1>();  // next phase needs old b2 (oldest 1 in flight)
    __builtin_amdgcn_s_barrier();

    // ---- P1: lo-mi x niB ----
#pragma unroll
    for (int s = 0; s < 2; s++)
      bfb[s] = *(const bf16x8*)&Bs[buf][((NF - 1) * 64 + wn * 16 + l15) * 64 +
                                        (((s << 2) | quad) ^ cgx) * 8];
    if (pf) sb2(buf ^ 1, k1);
    __builtin_amdgcn_s_barrier();
    LGKM0();
    __builtin_amdgcn_s_setprio(1);
#pragma unroll
    for (int mi = 0; mi < 4; mi++)
#pragma unroll
      for (int s = 0; s < 2; s++)
        acc[mi][NF - 1] = mfma16(af[mi][s], bfb[s], acc[mi][NF - 1]);
    __builtin_amdgcn_s_setprio(0);
    vmw<1 + S1>();  // next phase needs old b3 (oldest 2)
    __builtin_amdgcn_s_barrier();

    // ---- P2: hi-mi x niB ----
#pragma unroll
    for (int mi = 0; mi < 4; mi++)
#pragma unroll
      for (int s = 0; s < 2; s++)
        af[mi][s] = *(const bf16x8*)&As[buf][(128 + wm * 64 + mi * 16 + l15) * 64 +
                                             (((s << 2) | quad) ^ cgx) * 8];
    if (pf) sb3(buf ^ 1, k1);
    __builtin_amdgcn_s_barrier();
    LGKM0();
    __builtin_amdgcn_s_setprio(1);
#pragma unroll
    for (int mi = 0; mi < 4; mi++)
#pragma unroll
      for (int s = 0; s < 2; s++)
        acc[mi + 4][NF - 1] = mfma16(af[mi][s], bfb[s], acc[mi + 4][NF - 1]);
    __builtin_amdgcn_s_setprio(0);
    __builtin_amdgcn_s_barrier();

    // ---- P3: hi-mi x niA ----
#pragma unroll
    for (int ni = 0; ni < NA; ni++)
#pragma unroll
      for (int s = 0; s < 2; s++)
        bfa[ni][s] = *(const bf16x8*)&Bs[buf][(ni * 64 + wn * 16 + l15) * 64 +
                                              (((s << 2) | quad) ^ cgx) * 8];
    __builtin_amdgcn_s_barrier();
    LGKM0();
    __builtin_amdgcn_s_setprio(1);
#pragma unroll
    for (int mi = 0; mi < 4; mi++)
#pragma unroll
      for (int ni = 0; ni < NA; ni++)
#pragma unroll
        for (int s = 0; s < 2; s++)
          acc[mi + 4][ni] = mfma16(af[mi][s], bfa[ni][s], acc[mi + 4][ni]);
    __builtin_amdgcn_s_setprio(0);
    vmw<3>();  // next tile's P0 needs new b1 (oldest 4/3 of 7/6... >=3 safe both)
    __builtin_amdgcn_s_barrier();
  }

  // epilogue: C/D layout col=l15, row=quad*4+r
#pragma unroll
  for (int mi = 0; mi < 8; mi++)
#pragma unroll
    for (int ni = 0; ni < NF; ni++) {
      size_t row = (size_t)bm + (mi >> 2) * 128 + wm * 64 + (mi & 3) * 16 + quad * 4;
      size_t col = (size_t)bn + ni * 64 + wn * 16 + l15;
#pragma unroll
      for (int r = 0; r < 4; r++)
        C[(row + r) * N + col] = acc[mi][ni][r];
    }
}

// ---------------- RoPE + scatter ----------------
__global__ void rope_scatter(const float* __restrict__ qkv, bf16_t* __restrict__ Qb,
                             bf16_t* __restrict__ Kb, bf16_t* __restrict__ Vt,
                             float* __restrict__ kOut, float* __restrict__ vOut) {
  int idx = blockIdx.x * 256 + threadIdx.x;
  int t = idx / 3072;
  int p = idx - t * 3072;
  const float NEG_L2T_64 = -0.20762050593046f;  // -log2(10000)/64
  const float SS = 0.08838834764831845f * 1.4426950408889634f;  // SCALE*log2(e)
  if (p < 2048) {  // Q
    int hh = p >> 6, pr = p & 63;
    int d0 = pr << 1;
    const float* src = qkv + (size_t)t * QKVN + hh * HD + d0;
    float a = src[0], b = src[1];
    int j0 = d0 & 63, j1 = (d0 + 1) & 63;
    float th0 = (float)t * exp2f((float)j0 * NEG_L2T_64);
    float th1 = (float)t * exp2f((float)j1 * NEG_L2T_64);
    float o0 = (a * cosf(th0) - b * sinf(th0)) * SS;
    float o1 = (b * cosf(th1) + a * sinf(th1)) * SS;
    bf16_t* dst = Qb + ((size_t)hh * SEQ + t) * HD + d0;
    dst[0] = (bf16_t)o0;
    dst[1] = (bf16_t)o1;
  } else if (p < 2560) {  // K
    int q2 = p - 2048;
    int kh = q2 >> 6, pr = q2 & 63;
    int d0 = pr << 1;
    const float* src = qkv + (size_t)t * QKVN + 4096 + kh * HD + d0;
    float a = src[0], b = src[1];
    int j0 = d0 & 63, j1 = (d0 + 1) & 63;
    float th0 = (float)t * exp2f((float)j0 * NEG_L2T_64);
    float th1 = (float)t * exp2f((float)j1 * NEG_L2T_64);
    float o0 = a * cosf(th0) - b * sinf(th0);
    float o1 = b * cosf(th1) + a * sinf(th1);
    bf16_t* dst = Kb + ((size_t)kh * SEQ + t) * HD + d0;
    dst[0] = (bf16_t)o0;
    dst[1] = (bf16_t)o1;
#pragma unroll
    for (int rep = 0; rep < 4; rep++) {
      float* kp = kOut + ((size_t)(kh * 4 + rep) * SEQ + t) * HD + d0;
      kp[0] = o0;
      kp[1] = o1;
    }
  } else {  // V
    int q2 = p - 2560;
    int kh = q2 >> 6, pr = q2 & 63;
    int d0 = pr << 1;
    const float* src = qkv + (size_t)t * QKVN + 5120 + kh * HD + d0;
    float a = src[0], b = src[1];
#pragma unroll
    for (int rep = 0; rep < 4; rep++) {
      float* vp = vOut + ((size_t)(kh * 4 + rep) * SEQ + t) * HD + d0;
      vp[0] = a;
      vp[1] = b;
    }
    // permuted key position for attention's PV slot ordering
    int tp = (t & ~31) + ((t & 12) << 1) + (t & 3) + ((t & 16) >> 2);
    Vt[((size_t)kh * HD + d0) * SEQ + tp] = (bf16_t)a;
    Vt[((size_t)kh * HD + d0 + 1) * SEQ + tp] = (bf16_t)b;
  }
}

// ---------------- Flash attention ----------------
__global__ __launch_bounds__(512, 2) void attn_kernel(const bf16_t* __restrict__ Qb,
                                                      const bf16_t* __restrict__ Kb,
                                                      const bf16_t* __restrict__ Vt,
                                                      bf16_t* __restrict__ AO) {
  __shared__ bf16_t Ks[2][8192];  // [buf][kc(4)][key(64)][d(32)]
  __shared__ bf16_t Vs[2][8192];  // [buf][kt(2)][d(128)][slot(32)]
  const int h = blockIdx.y, kh = h >> 2;
  const int qbase = blockIdx.x * 256;
  const int w = threadIdx.x >> 6, lane = threadIdx.x & 63;
  const int l15 = lane & 15, quad = lane >> 4;
  const bf16_t* KbH = Kb + (size_t)kh * SEQ * HD;
  const bf16_t* VtH = Vt + (size_t)kh * HD * SEQ;

  bf16x8 qf[2][4];
#pragma unroll
  for (int nq = 0; nq < 2; nq++) {
    const bf16_t* qp = Qb + ((size_t)h * SEQ + qbase + w * 32 + nq * 16 + l15) * HD + quad * 8;
#pragma unroll
    for (int kc = 0; kc < 4; kc++) qf[nq][kc] = *(const bf16x8*)(qp + kc * 32);
  }

  f32x4 acc[8][2] = {};
  float rsum[2] = {0.f, 0.f};

  auto stage = [&](int buf, int kt0) {
    if (w < 4) {
      int kc = w;
#pragma unroll
      for (int kg = 0; kg < 4; kg++) {
        const bf16_t* g = KbH + (size_t)(kt0 + kg * 16 + (lane >> 2)) * HD + kc * 32 + (lane & 3) * 8;
        async16(g, &Ks[buf][kc * 2048 + kg * 512]);
      }
    } else {
      int vi = w - 4, kt = vi >> 1, dg0 = (vi & 1) * 4;
#pragma unroll
      for (int j = 0; j < 4; j++) {
        int dg = dg0 + j;
        const bf16_t* g = VtH + (size_t)(dg * 16 + (lane >> 2)) * SEQ + kt0 + kt * 32 + (lane & 3) * 8;
        async16(g, &Vs[buf][kt * 4096 + dg * 512]);
      }
    }
  };

  stage(0, 0);
  int buf = 0;

  for (int kt0 = 0; kt0 < SEQ; kt0 += 64, buf ^= 1) {
    __syncthreads();
    if (kt0 + 64 < SEQ) stage(buf ^ 1, kt0 + 64);

    f32x4 sacc[4][2] = {};
#pragma unroll
    for (int mi = 0; mi < 4; mi++)
#pragma unroll
      for (int kc = 0; kc < 4; kc++) {
        bf16x8 kf = *(const bf16x8*)(&Ks[buf][(kc * 64 + mi * 16 + l15) * 32 + quad * 8]);
#pragma unroll
        for (int nq = 0; nq < 2; nq++)
          sacc[mi][nq] = mfma16(kf, qf[nq][kc], sacc[mi][nq]);
      }

    int pk[4][2][2];
#pragma unroll
    for (int mi = 0; mi < 4; mi++)
#pragma unroll
      for (int nq = 0; nq < 2; nq++) {
        float p0 = exp2f(sacc[mi][nq][0]);
        float p1 = exp2f(sacc[mi][nq][1]);
        float p2 = exp2f(sacc[mi][nq][2]);
        float p3 = exp2f(sacc[mi][nq][3]);
        rsum[nq] += (p0 + p1) + (p2 + p3);
        pk[mi][nq][0] = pack2(p0, p1);
        pk[mi][nq][1] = pack2(p2, p3);
      }

#pragma unroll
    for (int kt = 0; kt < 2; kt++) {
#pragma unroll
      for (int nq = 0; nq < 2; nq++) {
        int4v dw;
        dw[0] = pk[2 * kt][nq][0];
        dw[1] = pk[2 * kt][nq][1];
        dw[2] = pk[2 * kt + 1][nq][0];
        dw[3] = pk[2 * kt + 1][nq][1];
        bf16x8 pf = __builtin_bit_cast(bf16x8, dw);
#pragma unroll
        for (int dt = 0; dt < 8; dt++) {
          bf16x8 vf = *(const bf16x8*)(&Vs[buf][(kt * 128 + dt * 16 + l15) * 32 + quad * 8]);
          acc[dt][nq] = mfma16(vf, pf, acc[dt][nq]);
        }
      }
    }
  }

#pragma unroll
  for (int nq = 0; nq < 2; nq++) {
    float rs = rsum[nq];
    rs += __shfl_xor(rs, 16);
    rs += __shfl_xor(rs, 32);
    float inv = 1.0f / rs;
    int q = qbase + w * 32 + nq * 16 + l15;
#pragma unroll
    for (int dt = 0; dt < 8; dt++) {
      bf16x4 o = { (bf16_t)(acc[dt][nq][0] * inv), (bf16_t)(acc[dt][nq][1] * inv),
                   (bf16_t)(acc[dt][nq][2] * inv), (bf16_t)(acc[dt][nq][3] * inv) };
      *(bf16x4*)(AO + (size_t)q * DIM + h * HD + dt * 16 + quad * 4) = o;
    }
  }
}

extern "C" void kernel_launch(void* const* d_in, const int* in_sizes, int n_in,
                              void* d_out, int out_size, void* d_ws, size_t ws_size,
                              hipStream_t stream) {
  const float* x = (const float*)d_in[0];
  const float* wq = (const float*)d_in[1];
  const float* wk = (const float*)d_in[2];
  const float* wv = (const float*)d_in[3];
  const float* wo = (const float*)d_in[4];
  float* out = (float*)d_out;
  float* kOut = out + (size_t)SEQ * DIM;
  float* vOut = kOut + (size_t)NH * SEQ * HD;

  char* ws = (char*)d_ws;
  bf16_t* Xb = (bf16_t*)ws;                          // 16 MB; later aliased as AO
  bf16_t* WT = (bf16_t*)(ws + 16777216);             // 48 MB: [wq^T|wk^T|wv^T]
  float* QKV = (float*)(ws + 67108864);              // 48 MB fp32
  bf16_t* WoT = (bf16_t*)(ws + 67108864);            // alias (QKV dead by then)
  bf16_t* Qb = (bf16_t*)(ws + 117440512);            // 16 MB
  bf16_t* Kb = (bf16_t*)(ws + 134217728);            // 4 MB
  bf16_t* Vt = (bf16_t*)(ws + 138412032);            // 4 MB (slot-permuted keys)
  bf16_t* AO = Xb;

  dim3 tb(32, 8);
  cast_x<<<8192, 256, 0, stream>>>(x, Xb);
  tcast<<<dim3(128, 128), tb, 0, stream>>>(wq, WT, 4096, 4096);
  tcast<<<dim3(32, 128), tb, 0, stream>>>(wk, WT + (size_t)4096 * 4096, 1024, 4096);
  tcast<<<dim3(32, 128), tb, 0, stream>>>(wv, WT + (size_t)5120 * 4096, 1024, 4096);
  gemm256<3><<<dim3(32, 8), 512, 0, stream>>>(Xb, WT, QKV, 2048, 6144, 4096);
  rope_scatter<<<24576, 256, 0, stream>>>(QKV, Qb, Kb, Vt, kOut, vOut);
  tcast<<<dim3(128, 128), tb, 0, stream>>>(wo, WoT, 4096, 4096);
  attn_kernel<<<dim3(8, 32), 512, 0, stream>>>(Qb, Kb, Vt, AO);
  gemm256<2><<<dim3(32, 8), 512, 0, stream>>>(AO, WoT, out, 2048, 4096, 4096);
}

// Round 3
// 537.813 us; speedup vs baseline: 1.1296x; 1.0266x over previous
//
#include <hip/hip_runtime.h>
#include <cstdint>
#include <cstddef>

#define DIM 4096
#define SEQ 2048
#define NH 32
#define NKV 8
#define HD 128
#define QKVN 6144

typedef __bf16 bf16_t;
typedef __bf16 bf16x8 __attribute__((ext_vector_type(8)));
typedef __bf16 bf16x4 __attribute__((ext_vector_type(4)));
typedef __bf16 bf16x2 __attribute__((ext_vector_type(2)));
typedef float f32x4 __attribute__((ext_vector_type(4)));
typedef int int4v __attribute__((ext_vector_type(4)));

__device__ __forceinline__ f32x4 mfma16(bf16x8 a, bf16x8 b, f32x4 c) {
  return __builtin_amdgcn_mfma_f32_16x16x32_bf16(a, b, c, 0, 0, 0);
}

__device__ __forceinline__ void async16(const bf16_t* g, bf16_t* l) {
  __builtin_amdgcn_global_load_lds((__attribute__((address_space(1))) void*)g,
                                   (__attribute__((address_space(3))) void*)l,
                                   16, 0, 0);
}

__device__ __forceinline__ int pack2(float a, float b) {
  bf16x2 h = { (bf16_t)a, (bf16_t)b };
  return __builtin_bit_cast(int, h);
}

// rule #18: inline-asm waits must be followed by sched_barrier(0)
#define LGKM0() do { asm volatile("s_waitcnt lgkmcnt(0)" ::: "memory"); \
                     __builtin_amdgcn_sched_barrier(0); } while (0)

template <int N> __device__ __forceinline__ void vmw() {
  if constexpr (N == 6) asm volatile("s_waitcnt vmcnt(6)" ::: "memory");
  else if constexpr (N == 7) asm volatile("s_waitcnt vmcnt(7)" ::: "memory");
  __builtin_amdgcn_sched_barrier(0);
}

// ---------------- cast x (fp32 -> bf16), 4 elems/thread ----------------
__global__ void cast_x(const float* __restrict__ x, bf16_t* __restrict__ xb) {
  int i = blockIdx.x * 256 + threadIdx.x;
  const float4 v = ((const float4*)x)[i];
  bf16x4 o = { (bf16_t)v.x, (bf16_t)v.y, (bf16_t)v.z, (bf16_t)v.w };
  *(bf16x4*)(xb + (size_t)i * 4) = o;
}

// ------- transpose-cast: src fp32 (Kdim x Ncols) -> dst bf16 (Ncols x Kdim) -------
__global__ void tcast(const float* __restrict__ src, bf16_t* __restrict__ dst,
                      int Ncols, int Kdim) {
  __shared__ float tile[32][33];
  int n0 = blockIdx.x * 32, k0 = blockIdx.y * 32;
  int tx = threadIdx.x, ty = threadIdx.y;  // 32 x 8
#pragma unroll
  for (int r = 0; r < 4; r++)
    tile[ty + 8 * r][tx] = src[(size_t)(k0 + ty + 8 * r) * Ncols + n0 + tx];
  __syncthreads();
#pragma unroll
  for (int r = 0; r < 4; r++)
    dst[(size_t)(n0 + ty + 8 * r) * Kdim + k0 + tx] = (bf16_t)tile[tx][ty + 8 * r];
}

// ---------------- GEMM: 256 x (NF*64) tile, BK=64, 8 waves -------------------
// m201-style schedule: loop iter = 2 K-tiles (buf0,buf1); uniform 16-MFMA
// phases (NF=3: 3/tile {lo x n01, hi x n01, all x n2}; NF=2: 2/tile); each
// tile's full stage (NLOAD=4+NF loads) issued in its LAST phase after
// lgkm0+barrier (no DMA/ds_read race), consumed 3 phases later; ONE
// vmcnt(NLOAD) per tile keeps the next tile's loads in flight across 3
// barriers.  Full (row&7) XOR swizzle (verified: 0 bank conflicts).
// Tail kept uniform by wrap-staging garbage (k & (K-1)) into dead buffers.
template <int NF>
__global__ __launch_bounds__(512) void gemm256(const bf16_t* __restrict__ A,
                                               const bf16_t* __restrict__ Bt,
                                               float* __restrict__ C,
                                               int M, int N, int K) {
  constexpr int NLOAD = 4 + NF;
  __shared__ bf16_t As[2][16384];
  __shared__ bf16_t Bs[2][NF * 4096];
  const int t = threadIdx.x;
  const int lane = t & 63;
  const int l15 = lane & 15, quad = lane >> 4;
  const int w = t >> 6, wm = w >> 2, wn = w & 3;  // 2 x 4 wave grid
  const int cgx = l15 & 7;

  // bijective XCD swizzle (nwg == 256): each XCD owns one M-strip.
  const int gx = gridDim.x;
  const int nwg = gx * gridDim.y;
  const int id = blockIdx.y * gx + blockIdx.x;
  const int swz = (id & 7) * (nwg >> 3) + (id >> 3);
  const int bm = (swz / gx) * 256, bn = (swz % gx) * (NF * 64);

  // staging: thread t -> row t>>3 within a 64-row group; LDS col-group t&7
  // holds global col-group (t&7)^(row&7)  (self-inverse swizzle)
  const int srow = t >> 3;
  const int scol = ((t & 7) ^ (srow & 7)) << 3;
  const bf16_t* gA = A + (size_t)(bm + srow) * K + scol;
  const bf16_t* gB = Bt + (size_t)(bn + srow) * K + scol;
  const int ldst = t * 8;

  f32x4 acc[8][NF] = {};

  auto stageT = [&](int b2, int kk) {
    async16(gA + kk, &As[b2][ldst]);
    async16(gA + (size_t)64 * K + kk, &As[b2][4096 + ldst]);
    async16(gA + (size_t)128 * K + kk, &As[b2][8192 + ldst]);
    async16(gA + (size_t)192 * K + kk, &As[b2][12288 + ldst]);
    async16(gB + kk, &Bs[b2][ldst]);
    async16(gB + (size_t)64 * K + kk, &Bs[b2][4096 + ldst]);
    if constexpr (NF == 3) async16(gB + (size_t)128 * K + kk, &Bs[b2][8192 + ldst]);
  };

  // prologue: stage tile0+tile1; wait tile0 only (tile1 stays in flight)
  stageT(0, 0);
  stageT(1, 64);
  vmw<NLOAD>();
  __builtin_amdgcn_s_barrier();

  auto tile = [&](int b2, int knext) {
    bf16x8 afl[4][2], afh[4][2], bf01[2][2], bf2[2];
    // ---- P0: lo-mi x n0,n1 ----
#pragma unroll
    for (int mi = 0; mi < 4; mi++)
#pragma unroll
      for (int s = 0; s < 2; s++)
        afl[mi][s] = *(const bf16x8*)&As[b2][(wm * 64 + mi * 16 + l15) * 64 +
                                            ((((s << 2) | quad) ^ cgx) << 3)];
#pragma unroll
    for (int ni = 0; ni < 2; ni++)
#pragma unroll
      for (int s = 0; s < 2; s++)
        bf01[ni][s] = *(const bf16x8*)&Bs[b2][(ni * 64 + wn * 16 + l15) * 64 +
                                              ((((s << 2) | quad) ^ cgx) << 3)];
    __builtin_amdgcn_s_barrier();
    LGKM0();
    __builtin_amdgcn_s_setprio(1);
#pragma unroll
    for (int mi = 0; mi < 4; mi++)
#pragma unroll
      for (int ni = 0; ni < 2; ni++)
#pragma unroll
        for (int s = 0; s < 2; s++)
          acc[mi][ni] = mfma16(afl[mi][s], bf01[ni][s], acc[mi][ni]);
    __builtin_amdgcn_s_setprio(0);
    __builtin_amdgcn_s_barrier();

    // ---- P1: hi-mi x n0,n1 ; NF==2: staging phase ----
#pragma unroll
    for (int mi = 0; mi < 4; mi++)
#pragma unroll
      for (int s = 0; s < 2; s++)
        afh[mi][s] = *(const bf16x8*)&As[b2][(128 + wm * 64 + mi * 16 + l15) * 64 +
                                             ((((s << 2) | quad) ^ cgx) << 3)];
    if constexpr (NF == 2) {
      LGKM0();  // all reads of this buf done before DMA overwrites it
      __builtin_amdgcn_s_barrier();
      stageT(b2, knext);
      __builtin_amdgcn_sched_barrier(0);
    } else {
      __builtin_amdgcn_s_barrier();
      LGKM0();
    }
    __builtin_amdgcn_s_setprio(1);
#pragma unroll
    for (int mi = 0; mi < 4; mi++)
#pragma unroll
      for (int ni = 0; ni < 2; ni++)
#pragma unroll
        for (int s = 0; s < 2; s++)
          acc[mi + 4][ni] = mfma16(afh[mi][s], bf01[ni][s], acc[mi + 4][ni]);
    __builtin_amdgcn_s_setprio(0);
    if constexpr (NF == 2) vmw<NLOAD>();  // prev tile's loads landed
    __builtin_amdgcn_s_barrier();

    // ---- P2 (NF==3 only): all-mi x n2 ; staging phase ----
    if constexpr (NF == 3) {
#pragma unroll
      for (int s = 0; s < 2; s++)
        bf2[s] = *(const bf16x8*)&Bs[b2][(128 + wn * 16 + l15) * 64 +
                                         ((((s << 2) | quad) ^ cgx) << 3)];
      LGKM0();
      __builtin_amdgcn_s_barrier();
      stageT(b2, knext);
      __builtin_amdgcn_sched_barrier(0);
      __builtin_amdgcn_s_setprio(1);
#pragma unroll
      for (int mi = 0; mi < 4; mi++)
#pragma unroll
        for (int s = 0; s < 2; s++) {
          acc[mi][2] = mfma16(afl[mi][s], bf2[s], acc[mi][2]);
          acc[mi + 4][2] = mfma16(afh[mi][s], bf2[s], acc[mi + 4][2]);
        }
      __builtin_amdgcn_s_setprio(0);
      vmw<NLOAD>();
      __builtin_amdgcn_s_barrier();
    }
  };

  const int nit = K >> 7;
  for (int i = 0; i < nit; ++i) {
    tile(0, ((i << 7) + 128) & (K - 1));
    tile(1, ((i << 7) + 192) & (K - 1));
  }

  // epilogue: C/D layout col=l15, row=quad*4+r
#pragma unroll
  for (int mi = 0; mi < 8; mi++)
#pragma unroll
    for (int ni = 0; ni < NF; ni++) {
      size_t row = (size_t)bm + (mi >> 2) * 128 + wm * 64 + (mi & 3) * 16 + quad * 4;
      size_t col = (size_t)bn + ni * 64 + wn * 16 + l15;
#pragma unroll
      for (int r = 0; r < 4; r++)
        C[(row + r) * N + col] = acc[mi][ni][r];
    }
}

// ---------------- RoPE + scatter ----------------
__global__ void rope_scatter(const float* __restrict__ qkv, bf16_t* __restrict__ Qb,
                             bf16_t* __restrict__ Kb, bf16_t* __restrict__ Vt,
                             float* __restrict__ kOut, float* __restrict__ vOut) {
  int idx = blockIdx.x * 256 + threadIdx.x;
  int t = idx / 3072;
  int p = idx - t * 3072;
  const float NEG_L2T_64 = -0.20762050593046f;  // -log2(10000)/64
  const float SS = 0.08838834764831845f * 1.4426950408889634f;  // SCALE*log2(e)
  if (p < 2048) {  // Q
    int hh = p >> 6, pr = p & 63;
    int d0 = pr << 1;
    const float* src = qkv + (size_t)t * QKVN + hh * HD + d0;
    float a = src[0], b = src[1];
    int j0 = d0 & 63, j1 = (d0 + 1) & 63;
    float th0 = (float)t * exp2f((float)j0 * NEG_L2T_64);
    float th1 = (float)t * exp2f((float)j1 * NEG_L2T_64);
    float o0 = (a * cosf(th0) - b * sinf(th0)) * SS;
    float o1 = (b * cosf(th1) + a * sinf(th1)) * SS;
    bf16_t* dst = Qb + ((size_t)hh * SEQ + t) * HD + d0;
    dst[0] = (bf16_t)o0;
    dst[1] = (bf16_t)o1;
  } else if (p < 2560) {  // K
    int q2 = p - 2048;
    int kh = q2 >> 6, pr = q2 & 63;
    int d0 = pr << 1;
    const float* src = qkv + (size_t)t * QKVN + 4096 + kh * HD + d0;
    float a = src[0], b = src[1];
    int j0 = d0 & 63, j1 = (d0 + 1) & 63;
    float th0 = (float)t * exp2f((float)j0 * NEG_L2T_64);
    float th1 = (float)t * exp2f((float)j1 * NEG_L2T_64);
    float o0 = a * cosf(th0) - b * sinf(th0);
    float o1 = b * cosf(th1) + a * sinf(th1);
    bf16_t* dst = Kb + ((size_t)kh * SEQ + t) * HD + d0;
    dst[0] = (bf16_t)o0;
    dst[1] = (bf16_t)o1;
#pragma unroll
    for (int rep = 0; rep < 4; rep++) {
      float* kp = kOut + ((size_t)(kh * 4 + rep) * SEQ + t) * HD + d0;
      kp[0] = o0;
      kp[1] = o1;
    }
  } else {  // V
    int q2 = p - 2560;
    int kh = q2 >> 6, pr = q2 & 63;
    int d0 = pr << 1;
    const float* src = qkv + (size_t)t * QKVN + 5120 + kh * HD + d0;
    float a = src[0], b = src[1];
#pragma unroll
    for (int rep = 0; rep < 4; rep++) {
      float* vp = vOut + ((size_t)(kh * 4 + rep) * SEQ + t) * HD + d0;
      vp[0] = a;
      vp[1] = b;
    }
    // permuted key position for attention's PV slot ordering
    int tp = (t & ~31) + ((t & 12) << 1) + (t & 3) + ((t & 16) >> 2);
    Vt[((size_t)kh * HD + d0) * SEQ + tp] = (bf16_t)a;
    Vt[((size_t)kh * HD + d0 + 1) * SEQ + tp] = (bf16_t)b;
  }
}

// ---------------- Flash attention ----------------
__global__ __launch_bounds__(512, 2) void attn_kernel(const bf16_t* __restrict__ Qb,
                                                      const bf16_t* __restrict__ Kb,
                                                      const bf16_t* __restrict__ Vt,
                                                      bf16_t* __restrict__ AO) {
  __shared__ bf16_t Ks[2][8192];  // [buf][kc(4)][key(64)][d(32)]
  __shared__ bf16_t Vs[2][8192];  // [buf][kt(2)][d(128)][slot(32)]
  const int h = blockIdx.y, kh = h >> 2;
  const int qbase = blockIdx.x * 256;
  const int w = threadIdx.x >> 6, lane = threadIdx.x & 63;
  const int l15 = lane & 15, quad = lane >> 4;
  const bf16_t* KbH = Kb + (size_t)kh * SEQ * HD;
  const bf16_t* VtH = Vt + (size_t)kh * HD * SEQ;

  bf16x8 qf[2][4];
#pragma unroll
  for (int nq = 0; nq < 2; nq++) {
    const bf16_t* qp = Qb + ((size_t)h * SEQ + qbase + w * 32 + nq * 16 + l15) * HD + quad * 8;
#pragma unroll
    for (int kc = 0; kc < 4; kc++) qf[nq][kc] = *(const bf16x8*)(qp + kc * 32);
  }

  f32x4 acc[8][2] = {};
  float rsum[2] = {0.f, 0.f};

  auto stage = [&](int buf, int kt0) {
    if (w < 4) {
      int kc = w;
#pragma unroll
      for (int kg = 0; kg < 4; kg++) {
        const bf16_t* g = KbH + (size_t)(kt0 + kg * 16 + (lane >> 2)) * HD + kc * 32 + (lane & 3) * 8;
        async16(g, &Ks[buf][kc * 2048 + kg * 512]);
      }
    } else {
      int vi = w - 4, kt = vi >> 1, dg0 = (vi & 1) * 4;
#pragma unroll
      for (int j = 0; j < 4; j++) {
        int dg = dg0 + j;
        const bf16_t* g = VtH + (size_t)(dg * 16 + (lane >> 2)) * SEQ + kt0 + kt * 32 + (lane & 3) * 8;
        async16(g, &Vs[buf][kt * 4096 + dg * 512]);
      }
    }
  };

  stage(0, 0);
  int buf = 0;

  for (int kt0 = 0; kt0 < SEQ; kt0 += 64, buf ^= 1) {
    __syncthreads();
    if (kt0 + 64 < SEQ) stage(buf ^ 1, kt0 + 64);

    f32x4 sacc[4][2] = {};
#pragma unroll
    for (int mi = 0; mi < 4; mi++)
#pragma unroll
      for (int kc = 0; kc < 4; kc++) {
        bf16x8 kf = *(const bf16x8*)(&Ks[buf][(kc * 64 + mi * 16 + l15) * 32 + quad * 8]);
#pragma unroll
        for (int nq = 0; nq < 2; nq++)
          sacc[mi][nq] = mfma16(kf, qf[nq][kc], sacc[mi][nq]);
      }

    int pk[4][2][2];
#pragma unroll
    for (int mi = 0; mi < 4; mi++)
#pragma unroll
      for (int nq = 0; nq < 2; nq++) {
        float p0 = exp2f(sacc[mi][nq][0]);
        float p1 = exp2f(sacc[mi][nq][1]);
        float p2 = exp2f(sacc[mi][nq][2]);
        float p3 = exp2f(sacc[mi][nq][3]);
        rsum[nq] += (p0 + p1) + (p2 + p3);
        pk[mi][nq][0] = pack2(p0, p1);
        pk[mi][nq][1] = pack2(p2, p3);
      }

#pragma unroll
    for (int kt = 0; kt < 2; kt++) {
#pragma unroll
      for (int nq = 0; nq < 2; nq++) {
        int4v dw;
        dw[0] = pk[2 * kt][nq][0];
        dw[1] = pk[2 * kt][nq][1];
        dw[2] = pk[2 * kt + 1][nq][0];
        dw[3] = pk[2 * kt + 1][nq][1];
        bf16x8 pf = __builtin_bit_cast(bf16x8, dw);
#pragma unroll
        for (int dt = 0; dt < 8; dt++) {
          bf16x8 vf = *(const bf16x8*)(&Vs[buf][(kt * 128 + dt * 16 + l15) * 32 + quad * 8]);
          acc[dt][nq] = mfma16(vf, pf, acc[dt][nq]);
        }
      }
    }
  }

#pragma unroll
  for (int nq = 0; nq < 2; nq++) {
    float rs = rsum[nq];
    rs += __shfl_xor(rs, 16);
    rs += __shfl_xor(rs, 32);
    float inv = 1.0f / rs;
    int q = qbase + w * 32 + nq * 16 + l15;
#pragma unroll
    for (int dt = 0; dt < 8; dt++) {
      bf16x4 o = { (bf16_t)(acc[dt][nq][0] * inv), (bf16_t)(acc[dt][nq][1] * inv),
                   (bf16_t)(acc[dt][nq][2] * inv), (bf16_t)(acc[dt][nq][3] * inv) };
      *(bf16x4*)(AO + (size_t)q * DIM + h * HD + dt * 16 + quad * 4) = o;
    }
  }
}

extern "C" void kernel_launch(void* const* d_in, const int* in_sizes, int n_in,
                              void* d_out, int out_size, void* d_ws, size_t ws_size,
                              hipStream_t stream) {
  const float* x = (const float*)d_in[0];
  const float* wq = (const float*)d_in[1];
  const float* wk = (const float*)d_in[2];
  const float* wv = (const float*)d_in[3];
  const float* wo = (const float*)d_in[4];
  float* out = (float*)d_out;
  float* kOut = out + (size_t)SEQ * DIM;
  float* vOut = kOut + (size_t)NH * SEQ * HD;

  char* ws = (char*)d_ws;
  bf16_t* Xb = (bf16_t*)ws;                          // 16 MB; later aliased as AO
  bf16_t* WT = (bf16_t*)(ws + 16777216);             // 48 MB: [wq^T|wk^T|wv^T]
  float* QKV = (float*)(ws + 67108864);              // 48 MB fp32
  bf16_t* WoT = (bf16_t*)(ws + 67108864);            // alias (QKV dead by then)
  bf16_t* Qb = (bf16_t*)(ws + 117440512);            // 16 MB
  bf16_t* Kb = (bf16_t*)(ws + 134217728);            // 4 MB
  bf16_t* Vt = (bf16_t*)(ws + 138412032);            // 4 MB (slot-permuted keys)
  bf16_t* AO = Xb;

  dim3 tb(32, 8);
  cast_x<<<8192, 256, 0, stream>>>(x, Xb);
  tcast<<<dim3(128, 128), tb, 0, stream>>>(wq, WT, 4096, 4096);
  tcast<<<dim3(32, 128), tb, 0, stream>>>(wk, WT + (size_t)4096 * 4096, 1024, 4096);
  tcast<<<dim3(32, 128), tb, 0, stream>>>(wv, WT + (size_t)5120 * 4096, 1024, 4096);
  gemm256<3><<<dim3(32, 8), 512, 0, stream>>>(Xb, WT, QKV, 2048, 6144, 4096);
  rope_scatter<<<24576, 256, 0, stream>>>(QKV, Qb, Kb, Vt, kOut, vOut);
  tcast<<<dim3(128, 128), tb, 0, stream>>>(wo, WoT, 4096, 4096);
  attn_kernel<<<dim3(8, 32), 512, 0, stream>>>(Qb, Kb, Vt, AO);
  gemm256<2><<<dim3(32, 8), 512, 0, stream>>>(AO, WoT, out, 2048, 4096, 4096);
}